// Round 5
// baseline (287.203 us; speedup 1.0000x reference)
//
#include <hip/hip_runtime.h>
#include <hip/hip_bf16.h>

#define D 1024
#define SLEN 2048
#define BS 16
#define MROWS (BS*SLEN)   // 32768
#define CROWS 32          // chunk rows (halved from 64: 2 blocks/CU, 4 waves/SIMD)
#define NCHUNK (MROWS/CROWS) // 1024 chunks
#define CPB (SLEN/CROWS)  // 64 chunks per batch

typedef __attribute__((ext_vector_type(8))) short short8;
typedef __attribute__((ext_vector_type(4))) float f32x4;

__device__ __forceinline__ short f2bf(float f) {
  __hip_bfloat16 h = __float2bfloat16(f);
  return __builtin_bit_cast(short, h);
}

// non-temporal float4 load: states is read exactly once (GEMM staging);
// bypass L2 retention so the 2 MB WkT stays L2-resident for the B stream.
__device__ __forceinline__ float4 ntload4(const float* p) {
  f32x4 v = __builtin_nontemporal_load((const f32x4*)p);
  float4 r; r.x = v.x; r.y = v.y; r.z = v.z; r.w = v.w; return r;
}

// ---------------- Kernel 1: Wk (k,n) fp32 -> blocked bf16 WkT ----------------
// WkT[(u*1024 + n)*8 + j] = bf16(Wk[(u*8+j)*1024 + n]), u=0..127.
__global__ __launch_bounds__(256) void wk_prep(const float* __restrict__ Wk,
                                               short* __restrict__ WkT) {
  const int g = blockIdx.x;        // 0..127
  const int t = threadIdx.x;
#pragma unroll
  for (int it = 0; it < 4; ++it) {
    const int n = it*256 + t;
    short8 p;
#pragma unroll
    for (int j = 0; j < 8; ++j)
      p[j] = f2bf(Wk[(size_t)(g*8 + j)*D + n]);
    *(short8*)(WkT + ((size_t)g*D + n)*8) = p;
  }
}

// ------- Kernel 2: energy GEMM + fused chunk-local softmax/attn partial -----
// R4 post-mortem: M=64 full-N fusion pinned 132KB LDS -> 1 block/CU and
// 128 acc regs -> 2 waves/SIMD; MfmaUtil 28% matched that model exactly.
// v5: M=32 chunk. LDS 67KB -> 2 blocks/CU; wave-tile 32x128 -> acc 64 AGPR,
// single-buffered frags, total <=128 unified regs -> 4 waves/SIMD. TLP now
// hides the B L2 latency (no SW prefetch ring needed at 4 waves), and
// co-resident blocks overlap staging with compute (m114). Cost: B L2
// traffic 2 GB (floor ~58us) -- still far below the current 102us.
__global__ __launch_bounds__(512, 4) void energy_gemm(
    const float* __restrict__ states, const short* __restrict__ WkT,
    const float* __restrict__ bk, const float* __restrict__ We,
    float* __restrict__ eraw, float* __restrict__ pattn,
    float* __restrict__ cmax, float* __restrict__ csum)
{
  __shared__ short Al[CROWS * 129 * 8];   // 66 KB: slot(row,u) = row*129 + u
  __shared__ float red2[CROWS * 8];       // cross-wave e reduction
  __shared__ float pfin[CROWS];           // p_s = exp(e_s - m_c)

  const int tid  = threadIdx.x;
  const int w    = tid >> 6;        // wave 0..7 -> col group w*128
  const int lane = tid & 63;
  const int quad = lane >> 4;       // k-unit within 32-chunk
  const int l16  = lane & 15;
  const int g    = blockIdx.x;      // chunk id 0..1023
  const int m0   = g * CROWS;

  // ---- one-time A staging: 32 rows x 1024 k, fp32 -> bf16 (non-temporal) ----
  {
    const int row = tid >> 4;        // 0..31
    const int u0  = tid & 15;        // 16 threads/row, u stride 16
    const float* Ag = states + (size_t)(m0 + row)*D;
#pragma unroll
    for (int i = 0; i < 8; ++i) {
      const int u = u0 + i*16;
      float4 x0 = ntload4(Ag + u*8);
      float4 x1 = ntload4(Ag + u*8 + 4);
      short8 p;
      p[0]=f2bf(x0.x); p[1]=f2bf(x0.y); p[2]=f2bf(x0.z); p[3]=f2bf(x0.w);
      p[4]=f2bf(x1.x); p[5]=f2bf(x1.y); p[6]=f2bf(x1.z); p[7]=f2bf(x1.w);
      *(short8*)(Al + ((size_t)row*129 + u)*8) = p;
    }
  }
  __syncthreads();

  f32x4 acc[2][2][4];               // [nc][mi][ni] : 64 f32 (AGPR side)
#pragma unroll
  for (int nc = 0; nc < 2; ++nc)
#pragma unroll
    for (int mi = 0; mi < 2; ++mi)
#pragma unroll
      for (int ni = 0; ni < 4; ++ni)
        acc[nc][mi][ni] = (f32x4){0.f, 0.f, 0.f, 0.f};

  const short* bbase = WkT + ((size_t)quad*D + w*128 + l16)*8;   // + ks*32768 + nc*512 + ni*128
  const short* abase = Al + ((size_t)l16*129 + quad)*8;          // + mi*16512 + ks*32

  // K-loop: single-buffered fragments (reg budget!), latency hidden by
  // 4 waves/SIMD TLP, not by SW pipelining (R2/R3 lesson).
#pragma unroll 2
  for (int ks = 0; ks < 32; ++ks) {
    short8 fa[2], fbx[4];
#pragma unroll
    for (int mi = 0; mi < 2; ++mi)
      fa[mi] = *(const short8*)(abase + mi*16512 + ks*32);
    const short* bp = bbase + (size_t)ks*32768;
#pragma unroll
    for (int nc = 0; nc < 2; ++nc) {
#pragma unroll
      for (int ni = 0; ni < 4; ++ni)
        fbx[ni] = *(const short8*)(bp + nc*512 + ni*128);
#pragma unroll
      for (int mi = 0; mi < 2; ++mi)
#pragma unroll
        for (int ni = 0; ni < 4; ++ni)
          acc[nc][mi][ni] = __builtin_amdgcn_mfma_f32_16x16x32_bf16(
              fa[mi], fbx[ni], acc[nc][mi][ni], 0, 0, 0);
    }
  }

  // ---- epilogue 1: esum[row] += tanh(relu(c + bk[n])) * We_k[n] ----
  float esum[8];
#pragma unroll
  for (int q = 0; q < 8; ++q) esum[q] = 0.f;
#pragma unroll
  for (int nc = 0; nc < 2; ++nc)
#pragma unroll
    for (int ni = 0; ni < 4; ++ni) {
      const int n = w*128 + nc*64 + ni*16 + l16;
      const float bkv = bk[n];
      const float wev = We[D + n];
#pragma unroll
      for (int mi = 0; mi < 2; ++mi)
#pragma unroll
        for (int r = 0; r < 4; ++r) {
          float x = acc[nc][mi][ni][r] + bkv;
          x = fmaxf(x, 0.f);
          float ex = __expf(2.f * x);
          float th = 1.f - 2.f/(ex + 1.f);
          esum[mi*4 + r] += th * wev;
        }
    }
#pragma unroll
  for (int dd = 1; dd < 16; dd <<= 1)
#pragma unroll
    for (int q = 0; q < 8; ++q)
      esum[q] += __shfl_xor(esum[q], dd, 64);

  if (l16 == 0) {
#pragma unroll
    for (int mi = 0; mi < 2; ++mi)
#pragma unroll
      for (int r = 0; r < 4; ++r)
        red2[(mi*16 + quad*4 + r)*8 + w] = esum[mi*4 + r];
  }
  __syncthreads();

  // ---- epilogue 2: chunk softmax stats (lanes 0..31 = 32 rows) ----
  if (tid < CROWS) {
    float e = 0.f;
#pragma unroll
    for (int wi = 0; wi < 8; ++wi) e += red2[tid*8 + wi];
    eraw[m0 + tid] = e;
    float mm = e;
#pragma unroll
    for (int dd = 1; dd < 32; dd <<= 1) mm = fmaxf(mm, __shfl_xor(mm, dd, 64));
    const float pv = __expf(e - mm);
    float ss = pv;
#pragma unroll
    for (int dd = 1; dd < 32; dd <<= 1) ss += __shfl_xor(ss, dd, 64);
    pfin[tid] = pv;
    if (tid == 0) { cmax[g] = mm; csum[g] = ss; }
  }
  __syncthreads();

  // ---- epilogue 3: partial_d = sum_s p_s * A_lds[s][d], d = 2*tid, 2*tid+1 ----
  {
    const int u    = tid >> 2;          // d/8
    const int joff = (tid & 3) * 2;     // d%8
    const short* ap = Al + (size_t)u*8 + joff;
    float a0 = 0.f, a1 = 0.f;
#pragma unroll 16
    for (int row = 0; row < CROWS; ++row) {
      const unsigned int bits = *(const unsigned int*)(ap + (size_t)row*1032);
      const float pv = pfin[row];
      const float lo = __builtin_bit_cast(float, bits << 16);
      const float hi = __builtin_bit_cast(float, bits & 0xffff0000u);
      a0 = fmaf(pv, lo, a0);
      a1 = fmaf(pv, hi, a1);
    }
    float2 o; o.x = a0; o.y = a1;
    *(float2*)(pattn + (size_t)g*D + 2*tid) = o;
  }
}

// ---------- Kernel 3: combine 64 chunk-partials per batch (tiny) ------------
// m_b = max_c m_c ; S_b = sum_c exp(m_c-m_b)*sumexp_c ;
// wts = exp(e-m_b)/S_b ; attn = (sum_c exp(m_c-m_b)*partial_c)/S_b.
__global__ __launch_bounds__(256) void attn_finalize(
    const float* __restrict__ eraw, const float* __restrict__ pattn,
    const float* __restrict__ cmax, const float* __restrict__ csum,
    float* __restrict__ wts, float* __restrict__ attn)
{
  const int b = blockIdx.x;
  const int t = threadIdx.x;
  __shared__ float scl[CPB];
  __shared__ float stats[2];

  if (t < CPB) {
    const float m = cmax[b*CPB + t];
    float mm = m;
#pragma unroll
    for (int dd = 1; dd < 64; dd <<= 1) mm = fmaxf(mm, __shfl_xor(mm, dd, 64));
    const float e = __expf(m - mm);
    scl[t] = e;
    float s = e * csum[b*CPB + t];
#pragma unroll
    for (int dd = 1; dd < 64; dd <<= 1) s += __shfl_xor(s, dd, 64);
    if (t == 0) { stats[0] = mm; stats[1] = 1.f / s; }
  }
  __syncthreads();
  const float m_b = stats[0];
  const float inv = stats[1];

  // weights: 2048 per batch, 8 per thread
#pragma unroll
  for (int j = 0; j < 8; ++j) {
    const int s = j*256 + t;
    wts[(size_t)b*SLEN + s] = __expf(eraw[(size_t)b*SLEN + s] - m_b) * inv;
  }

  // attn: 4 cols per thread, combine 64 chunks
  float acc[4] = {0.f, 0.f, 0.f, 0.f};
#pragma unroll
  for (int c = 0; c < CPB; ++c) {
    const float sc = scl[c];
    const float* pp = pattn + ((size_t)(b*CPB + c))*D + t;
#pragma unroll
    for (int j = 0; j < 4; ++j)
      acc[j] = fmaf(sc, pp[j*256], acc[j]);
  }
#pragma unroll
  for (int j = 0; j < 4; ++j)
    attn[(size_t)b*D + j*256 + t] = acc[j] * inv;
}

extern "C" void kernel_launch(void* const* d_in, const int* in_sizes, int n_in,
                              void* d_out, int out_size, void* d_ws, size_t ws_size,
                              hipStream_t stream) {
  // inputs: 0=query 1=states 2=Wq 3=bq 4=Wk 5=bk 6=We 7=be
  // q-path terms are constant per softmax row -> cancel; dead code.
  const float* states = (const float*)d_in[1];
  const float* Wk     = (const float*)d_in[4];
  const float* bk     = (const float*)d_in[5];
  const float* We     = (const float*)d_in[6];
  float* out = (float*)d_out;            // [0:32768) attn_weights, [32768:49152) attn

  char* ws = (char*)d_ws;
  short* WkT   = (short*)ws;  ws += (size_t)D*D*sizeof(short);        // 2 MB
  float* eraw  = (float*)ws;  ws += (size_t)MROWS*sizeof(float);      // 128 KB
  float* pattn = (float*)ws;  ws += (size_t)NCHUNK*D*sizeof(float);   // 4 MB
  float* cmaxp = (float*)ws;  ws += (size_t)NCHUNK*sizeof(float);
  float* csump = (float*)ws;

  (void)in_sizes; (void)n_in; (void)out_size; (void)ws_size;

  wk_prep<<<128, 256, 0, stream>>>(Wk, WkT);
  energy_gemm<<<NCHUNK, 512, 0, stream>>>(states, WkT, bk, We, eraw, pattn, cmaxp, csump);
  attn_finalize<<<BS, 256, 0, stream>>>(eraw, pattn, cmaxp, csump, out, out + MROWS);
}

// Round 6
// 267.524 us; speedup vs baseline: 1.0736x; 1.0736x over previous
//
#include <hip/hip_runtime.h>
#include <hip/hip_bf16.h>

#define D 1024
#define SLEN 2048
#define BS 16
#define MROWS (BS*SLEN)   // 32768
#define CROWS 64          // chunk rows (back to 64: B L2 traffic 1 GB, ceiling 88%)
#define NCHUNK (MROWS/CROWS) // 512
#define CPB (SLEN/CROWS)  // 32 chunks per batch

typedef __attribute__((ext_vector_type(8))) short short8;
typedef __attribute__((ext_vector_type(4))) float f32x4;

__device__ __forceinline__ short f2bf(float f) {
  __hip_bfloat16 h = __float2bfloat16(f);
  return __builtin_bit_cast(short, h);
}

// non-temporal float4 load: states is read exactly once (GEMM staging);
// bypass L2 retention so the 2 MB WkT stays L2-resident for the B stream.
__device__ __forceinline__ float4 ntload4(const float* p) {
  f32x4 v = __builtin_nontemporal_load((const f32x4*)p);
  float4 r; r.x = v.x; r.y = v.y; r.z = v.z; r.w = v.w; return r;
}

// ---------------- Kernel 1: Wk (k,n) fp32 -> blocked bf16 WkT ----------------
// WkT[(u*1024 + n)*8 + j] = bf16(Wk[(u*8+j)*1024 + n]), u=0..127.
__global__ __launch_bounds__(256) void wk_prep(const float* __restrict__ Wk,
                                               short* __restrict__ WkT) {
  const int g = blockIdx.x;        // 0..127
  const int t = threadIdx.x;
#pragma unroll
  for (int it = 0; it < 4; ++it) {
    const int n = it*256 + t;
    short8 p;
#pragma unroll
    for (int j = 0; j < 8; ++j)
      p[j] = f2bf(Wk[(size_t)(g*8 + j)*D + n]);
    *(short8*)(WkT + ((size_t)g*D + n)*8) = p;
  }
}

// ------- Kernel 2: energy GEMM + fused chunk-local softmax/attn partial -----
// R4/R5 ledger: M=64 has L2-BW ceiling 88% but R4's 2 waves/SIMD couldn't
// hide B latency (MfmaUtil 28%); M=32 doubled B traffic -> L2 ceiling 45%
// (R5: 24%). v6 = M=64 with a 1024-thread block: 16 waves, wave tile 64x64
// -> acc 64 AGPR + ~46 VGPR live, fits the 128-reg budget of 4 waves/SIMD
// (R3's spill was its 32-VGPR staging transient; staged in 2 batches here).
// Same L2 traffic as R4, 2x the latency-hiding warps.
__global__ __launch_bounds__(1024, 4) void energy_gemm(
    const float* __restrict__ states, const short* __restrict__ WkT,
    const float* __restrict__ bk, const float* __restrict__ We,
    float* __restrict__ eraw, float* __restrict__ pattn,
    float* __restrict__ cmax, float* __restrict__ csum)
{
  __shared__ short Al[CROWS * 129 * 8];   // 132 KB: slot(row,u) = row*129 + u
  __shared__ float red2[CROWS * 16];      // 4 KB cross-wave e reduction
  __shared__ float pfin[CROWS];           // p_s = exp(e_s - m_c)

  const int tid  = threadIdx.x;
  const int w    = tid >> 6;        // wave 0..15 -> col group w*64
  const int lane = tid & 63;
  const int quad = lane >> 4;       // k-unit within 32-chunk
  const int l16  = lane & 15;
  const int g    = blockIdx.x;      // chunk id 0..511
  const int m0   = g * CROWS;

  // ---- one-time A staging: 64 rows x 1024 k, fp32 -> bf16 (non-temporal) ----
  // 1024 threads: 16 threads/row, u stride 16; two 4-pair batches keep the
  // transient at 8 float4 = 32 VGPR (R3 spill lesson).
  {
    const int row = tid >> 4;        // 0..63
    const int u0  = tid & 15;
#pragma unroll
    for (int half = 0; half < 2; ++half) {
      const float* Ag = states + (size_t)(m0 + row)*D;
      float4 xs[8];
#pragma unroll
      for (int i = 0; i < 4; ++i) {
        const int u = u0 + (half*4 + i)*16;
        xs[2*i]   = ntload4(Ag + u*8);
        xs[2*i+1] = ntload4(Ag + u*8 + 4);
      }
#pragma unroll
      for (int i = 0; i < 4; ++i) {
        const int u = u0 + (half*4 + i)*16;
        short8 p;
        p[0]=f2bf(xs[2*i].x);   p[1]=f2bf(xs[2*i].y);
        p[2]=f2bf(xs[2*i].z);   p[3]=f2bf(xs[2*i].w);
        p[4]=f2bf(xs[2*i+1].x); p[5]=f2bf(xs[2*i+1].y);
        p[6]=f2bf(xs[2*i+1].z); p[7]=f2bf(xs[2*i+1].w);
        *(short8*)(Al + ((size_t)row*129 + u)*8) = p;
      }
    }
  }
  __syncthreads();

  f32x4 acc[4][4];                  // 64 rows x 64 cols per wave: 64 f32 (AGPR)
#pragma unroll
  for (int mi = 0; mi < 4; ++mi)
#pragma unroll
    for (int ni = 0; ni < 4; ++ni)
      acc[mi][ni] = (f32x4){0.f, 0.f, 0.f, 0.f};

  const short* bbase = WkT + ((size_t)quad*D + w*64 + l16)*8;   // + ks*32768 + ni*128
  const short* abase = Al + ((size_t)l16*129 + quad)*8;         // + mi*16512 + ks*32

  // K-loop: single-buffered fragments; latency hidden by 4 waves/SIMD TLP.
#pragma unroll 2
  for (int ks = 0; ks < 32; ++ks) {
    short8 fa[4], fbx[4];
#pragma unroll
    for (int mi = 0; mi < 4; ++mi)
      fa[mi] = *(const short8*)(abase + mi*16512 + ks*32);
    const short* bp = bbase + (size_t)ks*32768;
#pragma unroll
    for (int ni = 0; ni < 4; ++ni)
      fbx[ni] = *(const short8*)(bp + ni*128);
#pragma unroll
    for (int mi = 0; mi < 4; ++mi)
#pragma unroll
      for (int ni = 0; ni < 4; ++ni)
        acc[mi][ni] = __builtin_amdgcn_mfma_f32_16x16x32_bf16(
            fa[mi], fbx[ni], acc[mi][ni], 0, 0, 0);
  }

  // ---- epilogue 1: esum[row] += tanh(relu(c + bk[n])) * We_k[n] ----
  float esum[16];
#pragma unroll
  for (int q = 0; q < 16; ++q) esum[q] = 0.f;
#pragma unroll
  for (int ni = 0; ni < 4; ++ni) {
    const int n = w*64 + ni*16 + l16;
    const float bkv = bk[n];
    const float wev = We[D + n];
#pragma unroll
    for (int mi = 0; mi < 4; ++mi)
#pragma unroll
      for (int r = 0; r < 4; ++r) {
        float x = acc[mi][ni][r] + bkv;
        x = fmaxf(x, 0.f);
        float ex = __expf(2.f * x);
        float th = 1.f - 2.f/(ex + 1.f);
        esum[mi*4 + r] += th * wev;
      }
  }
#pragma unroll
  for (int dd = 1; dd < 16; dd <<= 1)
#pragma unroll
    for (int q = 0; q < 16; ++q)
      esum[q] += __shfl_xor(esum[q], dd, 64);

  if (l16 == 0) {
#pragma unroll
    for (int mi = 0; mi < 4; ++mi)
#pragma unroll
      for (int r = 0; r < 4; ++r)
        red2[(mi*16 + quad*4 + r)*16 + w] = esum[mi*4 + r];
  }
  __syncthreads();

  // ---- epilogue 2: chunk softmax stats (lanes 0..63 = 64 rows) ----
  if (tid < CROWS) {
    float e = 0.f;
#pragma unroll
    for (int wi = 0; wi < 16; ++wi) e += red2[tid*16 + wi];
    eraw[m0 + tid] = e;
    float mm = e;
#pragma unroll
    for (int dd = 1; dd < 64; dd <<= 1) mm = fmaxf(mm, __shfl_xor(mm, dd, 64));
    const float pv = __expf(e - mm);
    float ss = pv;
#pragma unroll
    for (int dd = 1; dd < 64; dd <<= 1) ss += __shfl_xor(ss, dd, 64);
    pfin[tid] = pv;
    if (tid == 0) { cmax[g] = mm; csum[g] = ss; }
  }
  __syncthreads();

  // ---- epilogue 3: partial_d = sum_s p_s * A_lds[s][d], d = 2*t, 2*t+1 ----
  // (threads 0..511; b32 LDS reads, 2-way aliasing only; pfin is broadcast)
  if (tid < 512) {
    const int u    = tid >> 2;          // d/8
    const int joff = (tid & 3) * 2;     // d%8
    const short* ap = Al + (size_t)u*8 + joff;
    float a0 = 0.f, a1 = 0.f;
#pragma unroll 16
    for (int row = 0; row < CROWS; ++row) {
      const unsigned int bits = *(const unsigned int*)(ap + (size_t)row*1032);
      const float pv = pfin[row];
      const float lo = __builtin_bit_cast(float, bits << 16);
      const float hi = __builtin_bit_cast(float, bits & 0xffff0000u);
      a0 = fmaf(pv, lo, a0);
      a1 = fmaf(pv, hi, a1);
    }
    float2 o; o.x = a0; o.y = a1;
    *(float2*)(pattn + (size_t)g*D + 2*tid) = o;
  }
}

// ---------- Kernel 3: combine 32 chunk-partials per batch (tiny) ------------
// m_b = max_c m_c ; S_b = sum_c exp(m_c-m_b)*sumexp_c ;
// wts = exp(e-m_b)/S_b ; attn = (sum_c exp(m_c-m_b)*partial_c)/S_b.
__global__ __launch_bounds__(256) void attn_finalize(
    const float* __restrict__ eraw, const float* __restrict__ pattn,
    const float* __restrict__ cmax, const float* __restrict__ csum,
    float* __restrict__ wts, float* __restrict__ attn)
{
  const int b = blockIdx.x;
  const int t = threadIdx.x;
  __shared__ float scl[CPB];
  __shared__ float stats[2];

  if (t < CPB) {
    const float m = cmax[b*CPB + t];
    float mm = m;
#pragma unroll
    for (int dd = 1; dd < CPB; dd <<= 1) mm = fmaxf(mm, __shfl_xor(mm, dd, 64));
    const float e = __expf(m - mm);
    scl[t] = e;
    float s = e * csum[b*CPB + t];
#pragma unroll
    for (int dd = 1; dd < CPB; dd <<= 1) s += __shfl_xor(s, dd, 64);
    if (t == 0) { stats[0] = mm; stats[1] = 1.f / s; }
  }
  __syncthreads();
  const float m_b = stats[0];
  const float inv = stats[1];

  // weights: 2048 per batch, 8 per thread
#pragma unroll
  for (int j = 0; j < 8; ++j) {
    const int s = j*256 + t;
    wts[(size_t)b*SLEN + s] = __expf(eraw[(size_t)b*SLEN + s] - m_b) * inv;
  }

  // attn: 4 cols per thread, combine CPB chunks
  float acc[4] = {0.f, 0.f, 0.f, 0.f};
#pragma unroll
  for (int c = 0; c < CPB; ++c) {
    const float sc = scl[c];
    const float* pp = pattn + ((size_t)(b*CPB + c))*D + t;
#pragma unroll
    for (int j = 0; j < 4; ++j)
      acc[j] = fmaf(sc, pp[j*256], acc[j]);
  }
#pragma unroll
  for (int j = 0; j < 4; ++j)
    attn[(size_t)b*D + j*256 + t] = acc[j] * inv;
}

extern "C" void kernel_launch(void* const* d_in, const int* in_sizes, int n_in,
                              void* d_out, int out_size, void* d_ws, size_t ws_size,
                              hipStream_t stream) {
  // inputs: 0=query 1=states 2=Wq 3=bq 4=Wk 5=bk 6=We 7=be
  // q-path terms are constant per softmax row -> cancel; dead code.
  const float* states = (const float*)d_in[1];
  const float* Wk     = (const float*)d_in[4];
  const float* bk     = (const float*)d_in[5];
  const float* We     = (const float*)d_in[6];
  float* out = (float*)d_out;            // [0:32768) attn_weights, [32768:49152) attn

  char* ws = (char*)d_ws;
  short* WkT   = (short*)ws;  ws += (size_t)D*D*sizeof(short);        // 2 MB
  float* eraw  = (float*)ws;  ws += (size_t)MROWS*sizeof(float);      // 128 KB
  float* pattn = (float*)ws;  ws += (size_t)NCHUNK*D*sizeof(float);   // 2 MB
  float* cmaxp = (float*)ws;  ws += (size_t)NCHUNK*sizeof(float);
  float* csump = (float*)ws;

  (void)in_sizes; (void)n_in; (void)out_size; (void)ws_size;

  wk_prep<<<128, 256, 0, stream>>>(Wk, WkT);
  energy_gemm<<<NCHUNK, 1024, 0, stream>>>(states, WkT, bk, We, eraw, pattn, cmaxp, csump);
  attn_finalize<<<BS, 256, 0, stream>>>(eraw, pattn, cmaxp, csump, out, out + MROWS);
}